// Round 1
// baseline (285.788 us; speedup 1.0000x reference)
//
#include <hip/hip_runtime.h>
#include <hip/hip_bf16.h>
#include <math.h>

#define NB 4
#define NT 512
#define NC 256
#define NC2 512
#define NH 4

// ---------------- K0: decode mask (robust to bool-bytes vs int32 upload) ----
__global__ void k_mask(const unsigned char* __restrict__ raw, int* __restrict__ out) {
    __shared__ int s_bytes;
    if (threadIdx.x == 0) s_bytes = 0;
    __syncthreads();
    // Scan first 2048 bytes (safe under both layouts). If any 32-bit word > 1,
    // the buffer is byte-packed bools (random 0/1 bytes), else int32 0/1.
    int flag = 0;
    const unsigned* w = (const unsigned*)raw;
    for (int i = threadIdx.x; i < (NB * NT) / 4; i += blockDim.x)
        if (w[i] > 1u) flag = 1;
    if (flag) atomicOr(&s_bytes, 1);
    __syncthreads();
    const int ib = s_bytes;
    for (int i = threadIdx.x; i < NB * NT; i += blockDim.x) {
        int v = ib ? (int)raw[i] : ((const int*)raw)[i];
        out[i] = v ? 1 : 0;
    }
}

// ---------------- K1: channel max-pool (k=5, pad 2) + concat --------------
__global__ void k_pool(const float* __restrict__ x, float* __restrict__ xnew) {
    const int row = blockIdx.x;          // b*NT + t
    const int c = threadIdx.x;           // 0..255
    __shared__ float r[NC];
    r[c] = x[(size_t)row * NC + c];
    __syncthreads();
    float m = r[c];
    if (c - 1 >= 0) m = fmaxf(m, r[c - 1]);
    if (c - 2 >= 0) m = fmaxf(m, r[c - 2]);
    if (c + 1 < NC) m = fmaxf(m, r[c + 1]);
    if (c + 2 < NC) m = fmaxf(m, r[c + 2]);
    float* o = xnew + (size_t)row * NC2;
    o[c] = m;          // pooled half
    o[NC + c] = r[c];  // original half
}

// ---------------- K2: subj/obj projections (x_new @ W + b) -----------------
// 8 rows per block, thread = output column. 256 blocks.
__global__ void k_proj(const float* __restrict__ xnew,
                       const float* __restrict__ Ws, const float* __restrict__ bs,
                       const float* __restrict__ Wo, const float* __restrict__ bo,
                       float* __restrict__ subj, float* __restrict__ obj) {
    const int R = 8;
    const int r0 = blockIdx.x * R;
    const int c = threadIdx.x;
    __shared__ float xs[R][NC2];
    const float4* src = (const float4*)(xnew + (size_t)r0 * NC2);
    for (int u = threadIdx.x; u < R * (NC2 / 4); u += 256) {
        int r = u >> 7, q = u & 127;
        *(float4*)&xs[r][q * 4] = src[u];
    }
    __syncthreads();
    float accs[R], acco[R];
#pragma unroll
    for (int r = 0; r < R; ++r) { accs[r] = 0.f; acco[r] = 0.f; }
    for (int k = 0; k < NC2; ++k) {
        float ws = Ws[k * NC + c];
        float wo = Wo[k * NC + c];
        float xv0 = xs[0][k], xv1 = xs[1][k], xv2 = xs[2][k], xv3 = xs[3][k];
        float xv4 = xs[4][k], xv5 = xs[5][k], xv6 = xs[6][k], xv7 = xs[7][k];
        accs[0] = fmaf(xv0, ws, accs[0]); acco[0] = fmaf(xv0, wo, acco[0]);
        accs[1] = fmaf(xv1, ws, accs[1]); acco[1] = fmaf(xv1, wo, acco[1]);
        accs[2] = fmaf(xv2, ws, accs[2]); acco[2] = fmaf(xv2, wo, acco[2]);
        accs[3] = fmaf(xv3, ws, accs[3]); acco[3] = fmaf(xv3, wo, acco[3]);
        accs[4] = fmaf(xv4, ws, accs[4]); acco[4] = fmaf(xv4, wo, acco[4]);
        accs[5] = fmaf(xv5, ws, accs[5]); acco[5] = fmaf(xv5, wo, acco[5]);
        accs[6] = fmaf(xv6, ws, accs[6]); acco[6] = fmaf(xv6, wo, acco[6]);
        accs[7] = fmaf(xv7, ws, accs[7]); acco[7] = fmaf(xv7, wo, acco[7]);
    }
    const float bsv = bs[c], bov = bo[c];
#pragma unroll
    for (int r = 0; r < R; ++r) {
        subj[(size_t)(r0 + r) * NC + c] = accs[r] + bsv;
        obj[(size_t)(r0 + r) * NC + c] = acco[r] + bov;
    }
}

// ---------------- K3: rep[b,i,j,h] = relu(sum_c |subj[j,c]-obj[i,c]| Wt[c,h] + bt[h])
// 32x32 (i,j) tile per block; 2x2 pairs per thread; LDS-staged with +8 pad.
__global__ __launch_bounds__(256, 2) void k_rep(
    const float* __restrict__ subj, const float* __restrict__ obj,
    const float* __restrict__ Wt, const float* __restrict__ bt,
    float* __restrict__ attn) {
    const int bx = blockIdx.x;
    const int b = bx >> 8;
    const int rem = bx & 255;
    const int it = rem >> 4, jt = rem & 15;

    __shared__ float sj[32][NC + 8];
    __shared__ float ob[32][NC + 8];
    __shared__ float wt[NC][4];

    const int tid = threadIdx.x;
    {
        const float4* srcS = (const float4*)(subj + ((size_t)b * NT + jt * 32) * NC);
        const float4* srcO = (const float4*)(obj  + ((size_t)b * NT + it * 32) * NC);
        for (int u = tid; u < 32 * (NC / 4); u += 256) {
            int r = u >> 6, q = u & 63;
            *(float4*)&sj[r][q * 4] = srcS[u];
            *(float4*)&ob[r][q * 4] = srcO[u];
        }
        const float4* wsrc = (const float4*)Wt;   // W_t is (256,4) row-major
        for (int u = tid; u < NC; u += 256) *(float4*)&wt[u][0] = wsrc[u];
    }
    __syncthreads();

    const int tx = tid & 15;  // j sub-tile
    const int ty = tid >> 4;  // i sub-tile
    float acc[2][2][4];
#pragma unroll
    for (int ii = 0; ii < 2; ++ii)
#pragma unroll
        for (int jj = 0; jj < 2; ++jj)
#pragma unroll
            for (int h = 0; h < NH; ++h) acc[ii][jj][h] = 0.f;

    for (int c = 0; c < NC; c += 4) {
        float4 sA = *(const float4*)&sj[tx * 2 + 0][c];
        float4 sB = *(const float4*)&sj[tx * 2 + 1][c];
        float4 oA = *(const float4*)&ob[ty * 2 + 0][c];
        float4 oB = *(const float4*)&ob[ty * 2 + 1][c];
        float s[2][4] = {{sA.x, sA.y, sA.z, sA.w}, {sB.x, sB.y, sB.z, sB.w}};
        float o[2][4] = {{oA.x, oA.y, oA.z, oA.w}, {oB.x, oB.y, oB.z, oB.w}};
#pragma unroll
        for (int q = 0; q < 4; ++q) {
            float4 w = *(const float4*)&wt[c + q][0];
#pragma unroll
            for (int ii = 0; ii < 2; ++ii)
#pragma unroll
                for (int jj = 0; jj < 2; ++jj) {
                    float d = fabsf(s[jj][q] - o[ii][q]);
                    acc[ii][jj][0] = fmaf(d, w.x, acc[ii][jj][0]);
                    acc[ii][jj][1] = fmaf(d, w.y, acc[ii][jj][1]);
                    acc[ii][jj][2] = fmaf(d, w.z, acc[ii][jj][2]);
                    acc[ii][jj][3] = fmaf(d, w.w, acc[ii][jj][3]);
                }
        }
    }

    const float4 btv = *(const float4*)bt;
#pragma unroll
    for (int ii = 0; ii < 2; ++ii) {
        const int i = it * 32 + ty * 2 + ii;
#pragma unroll
        for (int jj = 0; jj < 2; ++jj) {
            const int j = jt * 32 + tx * 2 + jj;
            float4 r;
            r.x = fmaxf(acc[ii][jj][0] + btv.x, 0.f);
            r.y = fmaxf(acc[ii][jj][1] + btv.y, 0.f);
            r.z = fmaxf(acc[ii][jj][2] + btv.z, 0.f);
            r.w = fmaxf(acc[ii][jj][3] + btv.w, 0.f);
            *(float4*)&attn[(((size_t)b * NT + i) * NT + j) * NH] = r;
        }
    }
}

// ---------------- K4: softmax over j (per b,i,h) + post-softmax mask -------
__global__ void k_soft(float* __restrict__ attn, const int* __restrict__ mask) {
    const int bi = blockIdx.x;            // b*NT + i  (== mask index for i)
    const int b = bi >> 9;
    float4* row = (float4*)(attn + (size_t)bi * (NT * NH));  // [j][h] as float4 per j
    const int t = threadIdx.x;
    float4 v0 = row[t];
    float4 v1 = row[t + 256];

    float mx[4] = {fmaxf(v0.x, v1.x), fmaxf(v0.y, v1.y),
                   fmaxf(v0.z, v1.z), fmaxf(v0.w, v1.w)};
#pragma unroll
    for (int off = 32; off; off >>= 1) {
#pragma unroll
        for (int h = 0; h < 4; ++h) mx[h] = fmaxf(mx[h], __shfl_xor(mx[h], off));
    }
    __shared__ float redm[4][4], reds[4][4];
    const int wid = t >> 6, lane = t & 63;
    if (lane == 0) {
#pragma unroll
        for (int h = 0; h < 4; ++h) redm[wid][h] = mx[h];
    }
    __syncthreads();
#pragma unroll
    for (int h = 0; h < 4; ++h)
        mx[h] = fmaxf(fmaxf(redm[0][h], redm[1][h]), fmaxf(redm[2][h], redm[3][h]));

    float e0[4] = {expf(v0.x - mx[0]), expf(v0.y - mx[1]),
                   expf(v0.z - mx[2]), expf(v0.w - mx[3])};
    float e1[4] = {expf(v1.x - mx[0]), expf(v1.y - mx[1]),
                   expf(v1.z - mx[2]), expf(v1.w - mx[3])};
    float sm[4] = {e0[0] + e1[0], e0[1] + e1[1], e0[2] + e1[2], e0[3] + e1[3]};
#pragma unroll
    for (int off = 32; off; off >>= 1) {
#pragma unroll
        for (int h = 0; h < 4; ++h) sm[h] += __shfl_xor(sm[h], off);
    }
    if (lane == 0) {
#pragma unroll
        for (int h = 0; h < 4; ++h) reds[wid][h] = sm[h];
    }
    __syncthreads();
    float rinv[4];
#pragma unroll
    for (int h = 0; h < 4; ++h)
        rinv[h] = 1.0f / (reds[0][h] + reds[1][h] + reds[2][h] + reds[3][h]);

    const int mi = mask[bi];
    const int mj0 = mask[b * NT + t];
    const int mj1 = mask[b * NT + t + 256];
    float4 o0, o1;
    o0.x = (mi & mj0) ? 0.f : e0[0] * rinv[0];
    o0.y = (mi & mj0) ? 0.f : e0[1] * rinv[1];
    o0.z = (mi & mj0) ? 0.f : e0[2] * rinv[2];
    o0.w = (mi & mj0) ? 0.f : e0[3] * rinv[3];
    o1.x = (mi & mj1) ? 0.f : e1[0] * rinv[0];
    o1.y = (mi & mj1) ? 0.f : e1[1] * rinv[1];
    o1.z = (mi & mj1) ? 0.f : e1[2] * rinv[2];
    o1.w = (mi & mj1) ? 0.f : e1[3] * rinv[3];
    row[t] = o0;
    row[t + 256] = o1;
}

extern "C" void kernel_launch(void* const* d_in, const int* in_sizes, int n_in,
                              void* d_out, int out_size, void* d_ws, size_t ws_size,
                              hipStream_t stream) {
    const float* x      = (const float*)d_in[0];
    const float* W_subj = (const float*)d_in[1];
    const float* b_subj = (const float*)d_in[2];
    const float* W_obj  = (const float*)d_in[3];
    const float* b_obj  = (const float*)d_in[4];
    const float* W_t    = (const float*)d_in[5];
    const float* b_t    = (const float*)d_in[6];
    const unsigned char* mask_raw = (const unsigned char*)d_in[7];

    float* xnew = (float*)d_out;                           // NB*NT*NC2 floats
    float* attn = xnew + (size_t)NB * NT * NC2;            // NB*NT*NT*NH floats

    int* wmask  = (int*)d_ws;                              // NB*NT ints
    float* subj = (float*)d_ws + NB * NT;                  // NB*NT*NC
    float* obj  = subj + (size_t)NB * NT * NC;             // NB*NT*NC

    hipLaunchKernelGGL(k_mask, dim3(1), dim3(256), 0, stream, mask_raw, wmask);
    hipLaunchKernelGGL(k_pool, dim3(NB * NT), dim3(NC), 0, stream, x, xnew);
    hipLaunchKernelGGL(k_proj, dim3(NB * NT / 8), dim3(256), 0, stream,
                       xnew, W_subj, b_subj, W_obj, b_obj, subj, obj);
    hipLaunchKernelGGL(k_rep, dim3(NB * 16 * 16), dim3(256), 0, stream,
                       subj, obj, W_t, b_t, attn);
    hipLaunchKernelGGL(k_soft, dim3(NB * NT), dim3(256), 0, stream, attn, wmask);
}

// Round 3
// 187.104 us; speedup vs baseline: 1.5274x; 1.5274x over previous
//
#include <hip/hip_runtime.h>
#include <hip/hip_bf16.h>
#include <math.h>

#define NB 4
#define NT 512
#define NC 256
#define NC2 512
#define NH 4

// ---------------- K0: decode mask (robust to bool-bytes vs int32 upload) ----
__global__ void k_mask(const unsigned char* __restrict__ raw, int* __restrict__ out) {
    __shared__ int s_bytes;
    if (threadIdx.x == 0) s_bytes = 0;
    __syncthreads();
    int flag = 0;
    const unsigned* w = (const unsigned*)raw;
    for (int i = threadIdx.x; i < (NB * NT) / 4; i += blockDim.x)
        if (w[i] > 1u) flag = 1;
    if (flag) atomicOr(&s_bytes, 1);
    __syncthreads();
    const int ib = s_bytes;
    for (int i = threadIdx.x; i < NB * NT; i += blockDim.x) {
        int v = ib ? (int)raw[i] : ((const int*)raw)[i];
        out[i] = v ? 1 : 0;
    }
}

// ---------------- K1: channel max-pool (k=5, pad 2) + concat --------------
__global__ void k_pool(const float* __restrict__ x, float* __restrict__ xnew) {
    const int row = blockIdx.x;          // b*NT + t
    const int c = threadIdx.x;           // 0..255
    __shared__ float r[NC];
    r[c] = x[(size_t)row * NC + c];
    __syncthreads();
    float m = r[c];
    if (c - 1 >= 0) m = fmaxf(m, r[c - 1]);
    if (c - 2 >= 0) m = fmaxf(m, r[c - 2]);
    if (c + 1 < NC) m = fmaxf(m, r[c + 1]);
    if (c + 2 < NC) m = fmaxf(m, r[c + 2]);
    float* o = xnew + (size_t)row * NC2;
    o[c] = m;          // pooled half
    o[NC + c] = r[c];  // original half
}

// ---------------- K2: subj/obj projections (x_new @ W + b) -----------------
// BM=8 rows/block, thread = output column (256). x transposed in LDS (bcast
// b128 reads); weights register-prefetched 8 deep from global (L2).
__global__ __launch_bounds__(256) void k_proj(
    const float* __restrict__ xnew,
    const float* __restrict__ Ws, const float* __restrict__ bs,
    const float* __restrict__ Wo, const float* __restrict__ bo,
    float* __restrict__ subj, float* __restrict__ obj) {
    const int r0 = blockIdx.x * 8;
    const int c = threadIdx.x;
    __shared__ float xt[NC2][12];   // [k][row], stride 48B keeps b128 align

    {   // stage + transpose: r fast across lanes so LDS write banks spread
        const float* base = xnew + (size_t)r0 * NC2;
#pragma unroll
        for (int p = 0; p < 4; ++p) {
            int idx = p * 256 + threadIdx.x;
            int r = idx & 7;
            int k4 = idx >> 3;              // 0..127
            float4 v = *(const float4*)(base + r * NC2 + k4 * 4);
            xt[k4 * 4 + 0][r] = v.x;
            xt[k4 * 4 + 1][r] = v.y;
            xt[k4 * 4 + 2][r] = v.z;
            xt[k4 * 4 + 3][r] = v.w;
        }
    }
    __syncthreads();

    float acs[8], aco[8];
#pragma unroll
    for (int r = 0; r < 8; ++r) { acs[r] = 0.f; aco[r] = 0.f; }

    const float* wsp = Ws + c;
    const float* wop = Wo + c;
    float wsb[8], wob[8];
#pragma unroll
    for (int q = 0; q < 8; ++q) { wsb[q] = wsp[q * NC]; wob[q] = wop[q * NC]; }

    for (int kk = 0; kk < NC2; kk += 8) {
        float wsn[8], won[8];
        if (kk + 8 < NC2) {
#pragma unroll
            for (int q = 0; q < 8; ++q) {
                wsn[q] = wsp[(kk + 8 + q) * NC];
                won[q] = wop[(kk + 8 + q) * NC];
            }
        }
#pragma unroll
        for (int q = 0; q < 8; ++q) {
            float4 xa = *(const float4*)&xt[kk + q][0];
            float4 xb = *(const float4*)&xt[kk + q][4];
            float ws = wsb[q], wo = wob[q];
            acs[0] = fmaf(xa.x, ws, acs[0]); aco[0] = fmaf(xa.x, wo, aco[0]);
            acs[1] = fmaf(xa.y, ws, acs[1]); aco[1] = fmaf(xa.y, wo, aco[1]);
            acs[2] = fmaf(xa.z, ws, acs[2]); aco[2] = fmaf(xa.z, wo, aco[2]);
            acs[3] = fmaf(xa.w, ws, acs[3]); aco[3] = fmaf(xa.w, wo, aco[3]);
            acs[4] = fmaf(xb.x, ws, acs[4]); aco[4] = fmaf(xb.x, wo, aco[4]);
            acs[5] = fmaf(xb.y, ws, acs[5]); aco[5] = fmaf(xb.y, wo, aco[5]);
            acs[6] = fmaf(xb.z, ws, acs[6]); aco[6] = fmaf(xb.z, wo, aco[6]);
            acs[7] = fmaf(xb.w, ws, acs[7]); aco[7] = fmaf(xb.w, wo, aco[7]);
        }
#pragma unroll
        for (int q = 0; q < 8; ++q) { wsb[q] = wsn[q]; wob[q] = won[q]; }
    }

    const float bsv = bs[c], bov = bo[c];
#pragma unroll
    for (int r = 0; r < 8; ++r) {
        subj[(size_t)(r0 + r) * NC + c] = acs[r] + bsv;
        obj[(size_t)(r0 + r) * NC + c] = aco[r] + bov;
    }
}

// ---------------- K3: rep[b,i,j,h] = relu(sum_c |subj[j,c]-obj[i,c]| Wt[c,h] + bt[h])
// 64x64 (i,j) tile per block (grid=256); 4x4 pairs per thread (64 acc);
// c staged in 64-wide chunks, TRANSPOSED in LDS so inner reads are clean b128.
__global__ __launch_bounds__(256) void k_rep(
    const float* __restrict__ subj, const float* __restrict__ obj,
    const float* __restrict__ Wt, const float* __restrict__ bt,
    float* __restrict__ attn) {
    const int bx = blockIdx.x;
    const int b = bx >> 6;
    const int rem = bx & 63;
    const int it = rem >> 3, jt = rem & 7;
    const int i0 = it * 64, j0 = jt * 64;

    __shared__ float sjT[64][68];   // [c_local][j]
    __shared__ float obT[64][68];   // [c_local][i]
    __shared__ float wt4[NC][4];

    const int tid = threadIdx.x;
    {   // W_t (256x4) staged once
        float4 w = ((const float4*)Wt)[tid];
        *(float4*)&wt4[tid][0] = w;
    }

    const int tx = tid & 15;   // j group: js = j0 + 4*tx + jj
    const int ty = tid >> 4;   // i group: is = i0 + 4*ty + ii

    float acc[4][4][4];
#pragma unroll
    for (int ii = 0; ii < 4; ++ii)
#pragma unroll
        for (int jj = 0; jj < 4; ++jj)
#pragma unroll
            for (int h = 0; h < 4; ++h) acc[ii][jj][h] = 0.f;

    for (int cc = 0; cc < NC; cc += 64) {
        __syncthreads();   // waves done reading previous chunk (also covers wt4)
        // stage chunk transposed: 4 float4 per thread per matrix
#pragma unroll
        for (int p = 0; p < 4; ++p) {
            int u = p * 256 + tid;
            int j = u >> 4;            // 0..63
            int c4 = u & 15;           // 0..15
            float4 vs = *(const float4*)(subj + ((size_t)(b * NT) + j0 + j) * NC + cc + c4 * 4);
            float4 vo = *(const float4*)(obj  + ((size_t)(b * NT) + i0 + j) * NC + cc + c4 * 4);
            sjT[c4 * 4 + 0][j] = vs.x; sjT[c4 * 4 + 1][j] = vs.y;
            sjT[c4 * 4 + 2][j] = vs.z; sjT[c4 * 4 + 3][j] = vs.w;
            obT[c4 * 4 + 0][j] = vo.x; obT[c4 * 4 + 1][j] = vo.y;
            obT[c4 * 4 + 2][j] = vo.z; obT[c4 * 4 + 3][j] = vo.w;
        }
        __syncthreads();

#pragma unroll 4
        for (int cl = 0; cl < 64; ++cl) {
            float4 s4 = *(const float4*)&sjT[cl][tx * 4];
            float4 o4 = *(const float4*)&obT[cl][ty * 4];
            float4 w4 = *(const float4*)&wt4[cc + cl][0];
            float sv[4] = {s4.x, s4.y, s4.z, s4.w};
            float ov[4] = {o4.x, o4.y, o4.z, o4.w};
#pragma unroll
            for (int ii = 0; ii < 4; ++ii)
#pragma unroll
                for (int jj = 0; jj < 4; ++jj) {
                    float d = fabsf(sv[jj] - ov[ii]);
                    acc[ii][jj][0] = fmaf(d, w4.x, acc[ii][jj][0]);
                    acc[ii][jj][1] = fmaf(d, w4.y, acc[ii][jj][1]);
                    acc[ii][jj][2] = fmaf(d, w4.z, acc[ii][jj][2]);
                    acc[ii][jj][3] = fmaf(d, w4.w, acc[ii][jj][3]);
                }
        }
    }

    const float4 btv = *(const float4*)bt;
#pragma unroll
    for (int ii = 0; ii < 4; ++ii) {
        const int i = i0 + ty * 4 + ii;
#pragma unroll
        for (int jj = 0; jj < 4; ++jj) {
            const int j = j0 + tx * 4 + jj;
            float4 r;
            r.x = fmaxf(acc[ii][jj][0] + btv.x, 0.f);
            r.y = fmaxf(acc[ii][jj][1] + btv.y, 0.f);
            r.z = fmaxf(acc[ii][jj][2] + btv.z, 0.f);
            r.w = fmaxf(acc[ii][jj][3] + btv.w, 0.f);
            *(float4*)&attn[(((size_t)b * NT + i) * NT + j) * NH] = r;
        }
    }
}

// ---------------- K4: softmax over j (per b,i,h) + post-softmax mask -------
__global__ void k_soft(float* __restrict__ attn, const int* __restrict__ mask) {
    const int bi = blockIdx.x;            // b*NT + i
    const int b = bi >> 9;
    float4* row = (float4*)(attn + (size_t)bi * (NT * NH));
    const int t = threadIdx.x;
    float4 v0 = row[t];
    float4 v1 = row[t + 256];

    float mx[4] = {fmaxf(v0.x, v1.x), fmaxf(v0.y, v1.y),
                   fmaxf(v0.z, v1.z), fmaxf(v0.w, v1.w)};
#pragma unroll
    for (int off = 32; off; off >>= 1) {
#pragma unroll
        for (int h = 0; h < 4; ++h) mx[h] = fmaxf(mx[h], __shfl_xor(mx[h], off));
    }
    __shared__ float redm[4][4], reds[4][4];
    const int wid = t >> 6, lane = t & 63;
    if (lane == 0) {
#pragma unroll
        for (int h = 0; h < 4; ++h) redm[wid][h] = mx[h];
    }
    __syncthreads();
#pragma unroll
    for (int h = 0; h < 4; ++h)
        mx[h] = fmaxf(fmaxf(redm[0][h], redm[1][h]), fmaxf(redm[2][h], redm[3][h]));

    float e0[4] = {expf(v0.x - mx[0]), expf(v0.y - mx[1]),
                   expf(v0.z - mx[2]), expf(v0.w - mx[3])};
    float e1[4] = {expf(v1.x - mx[0]), expf(v1.y - mx[1]),
                   expf(v1.z - mx[2]), expf(v1.w - mx[3])};
    float sm[4] = {e0[0] + e1[0], e0[1] + e1[1], e0[2] + e1[2], e0[3] + e1[3]};
#pragma unroll
    for (int off = 32; off; off >>= 1) {
#pragma unroll
        for (int h = 0; h < 4; ++h) sm[h] += __shfl_xor(sm[h], off);
    }
    if (lane == 0) {
#pragma unroll
        for (int h = 0; h < 4; ++h) reds[wid][h] = sm[h];
    }
    __syncthreads();
    float rinv[4];
#pragma unroll
    for (int h = 0; h < 4; ++h)
        rinv[h] = 1.0f / (reds[0][h] + reds[1][h] + reds[2][h] + reds[3][h]);

    const int mi = mask[bi];
    const int mj0 = mask[b * NT + t];
    const int mj1 = mask[b * NT + t + 256];
    float4 o0, o1;
    o0.x = (mi & mj0) ? 0.f : e0[0] * rinv[0];
    o0.y = (mi & mj0) ? 0.f : e0[1] * rinv[1];
    o0.z = (mi & mj0) ? 0.f : e0[2] * rinv[2];
    o0.w = (mi & mj0) ? 0.f : e0[3] * rinv[3];
    o1.x = (mi & mj1) ? 0.f : e1[0] * rinv[0];
    o1.y = (mi & mj1) ? 0.f : e1[1] * rinv[1];
    o1.z = (mi & mj1) ? 0.f : e1[2] * rinv[2];
    o1.w = (mi & mj1) ? 0.f : e1[3] * rinv[3];
    row[t] = o0;
    row[t + 256] = o1;
}

extern "C" void kernel_launch(void* const* d_in, const int* in_sizes, int n_in,
                              void* d_out, int out_size, void* d_ws, size_t ws_size,
                              hipStream_t stream) {
    const float* x      = (const float*)d_in[0];
    const float* W_subj = (const float*)d_in[1];
    const float* b_subj = (const float*)d_in[2];
    const float* W_obj  = (const float*)d_in[3];
    const float* b_obj  = (const float*)d_in[4];
    const float* W_t    = (const float*)d_in[5];
    const float* b_t    = (const float*)d_in[6];
    const unsigned char* mask_raw = (const unsigned char*)d_in[7];

    float* xnew = (float*)d_out;                           // NB*NT*NC2 floats
    float* attn = xnew + (size_t)NB * NT * NC2;            // NB*NT*NT*NH floats

    int* wmask  = (int*)d_ws;                              // NB*NT ints
    float* subj = (float*)d_ws + NB * NT;                  // NB*NT*NC
    float* obj  = subj + (size_t)NB * NT * NC;             // NB*NT*NC

    hipLaunchKernelGGL(k_mask, dim3(1), dim3(256), 0, stream, mask_raw, wmask);
    hipLaunchKernelGGL(k_pool, dim3(NB * NT), dim3(NC), 0, stream, x, xnew);
    hipLaunchKernelGGL(k_proj, dim3(NB * NT / 8), dim3(256), 0, stream,
                       xnew, W_subj, b_subj, W_obj, b_obj, subj, obj);
    hipLaunchKernelGGL(k_rep, dim3(NB * 64), dim3(256), 0, stream,
                       subj, obj, W_t, b_t, attn);
    hipLaunchKernelGGL(k_soft, dim3(NB * NT), dim3(256), 0, stream, attn, wmask);
}

// Round 4
// 162.860 us; speedup vs baseline: 1.7548x; 1.1489x over previous
//
#include <hip/hip_runtime.h>
#include <hip/hip_bf16.h>
#include <math.h>

#define NB 4
#define NT 512
#define NC 256
#define NC2 512
#define NH 4

// ---------------- K0: decode mask (robust to bool-bytes vs int32 upload) ----
__global__ void k_mask(const unsigned char* __restrict__ raw, int* __restrict__ out) {
    __shared__ int s_bytes;
    if (threadIdx.x == 0) s_bytes = 0;
    __syncthreads();
    int flag = 0;
    const unsigned* w = (const unsigned*)raw;
    for (int i = threadIdx.x; i < (NB * NT) / 4; i += blockDim.x)
        if (w[i] > 1u) flag = 1;
    if (flag) atomicOr(&s_bytes, 1);
    __syncthreads();
    const int ib = s_bytes;
    for (int i = threadIdx.x; i < NB * NT; i += blockDim.x) {
        int v = ib ? (int)raw[i] : ((const int*)raw)[i];
        out[i] = v ? 1 : 0;
    }
}

// ---------------- K1+K2 fused: pool+concat -> xnew, then projections -------
// 8 rows/block, 512 threads: c = tid&255 (output col), kh = tid>>8 (K half).
// 2 waves/SIMD. Weights register-prefetched 8 deep; LDS reduce across halves.
__global__ __launch_bounds__(512) void k_poolproj(
    const float* __restrict__ x,
    const float* __restrict__ Ws, const float* __restrict__ bs,
    const float* __restrict__ Wo, const float* __restrict__ bo,
    float* __restrict__ xnew,
    float* __restrict__ subj, float* __restrict__ obj) {
    const int r0 = blockIdx.x * 8;
    const int tid = threadIdx.x;
    __shared__ float xraw[8][260];
    __shared__ float xp[8][260];
    __shared__ float xt[NC2][12];      // [k][row]
    __shared__ float red[256][17];

    // 1. stage x rows (8 x 256), coalesced, 1 float4/thread
    {
        int r = tid >> 6, c4 = tid & 63;
        float4 v = *(const float4*)(x + ((size_t)(r0 + r)) * NC + c4 * 4);
        *(float4*)&xraw[r][c4 * 4] = v;
    }
    __syncthreads();
    // 2. pooled = maxpool5 along channel
#pragma unroll
    for (int p = 0; p < 4; ++p) {
        int u = p * 512 + tid;
        int r = u >> 8, c = u & 255;
        float m = xraw[r][c];
        if (c >= 1) m = fmaxf(m, xraw[r][c - 1]);
        if (c >= 2) m = fmaxf(m, xraw[r][c - 2]);
        if (c <= 254) m = fmaxf(m, xraw[r][c + 1]);
        if (c <= 253) m = fmaxf(m, xraw[r][c + 2]);
        xp[r][c] = m;
    }
    __syncthreads();
    // 3. build xt transposed ([k][r]) and 4. write xnew coalesced
#pragma unroll
    for (int p = 0; p < 2; ++p) {
        int idx = p * 512 + tid;
        int r = idx & 7, k4 = idx >> 3;   // k4 0..127
        float4 v = (k4 < 64) ? *(const float4*)&xp[r][k4 * 4]
                             : *(const float4*)&xraw[r][(k4 - 64) * 4];
        xt[k4 * 4 + 0][r] = v.x; xt[k4 * 4 + 1][r] = v.y;
        xt[k4 * 4 + 2][r] = v.z; xt[k4 * 4 + 3][r] = v.w;
    }
#pragma unroll
    for (int p = 0; p < 2; ++p) {
        int u = p * 512 + tid;
        int r = u >> 7, k4 = u & 127;
        float4 v = (k4 < 64) ? *(const float4*)&xp[r][k4 * 4]
                             : *(const float4*)&xraw[r][(k4 - 64) * 4];
        *(float4*)(xnew + ((size_t)(r0 + r)) * NC2 + k4 * 4) = v;
    }
    __syncthreads();

    // GEMM: each half of threads does 256 of K=512
    const int c = tid & 255;
    const int kh = tid >> 8;
    const int kbase = kh * 256;

    float acs[8], aco[8];
#pragma unroll
    for (int r = 0; r < 8; ++r) { acs[r] = 0.f; aco[r] = 0.f; }

    const float* wsp = Ws + (size_t)kbase * NC + c;
    const float* wop = Wo + (size_t)kbase * NC + c;
    float wsb[8], wob[8];
#pragma unroll
    for (int q = 0; q < 8; ++q) { wsb[q] = wsp[q * NC]; wob[q] = wop[q * NC]; }

    for (int kk = 0; kk < 256; kk += 8) {
        float wsn[8], won[8];
        if (kk + 8 < 256) {
#pragma unroll
            for (int q = 0; q < 8; ++q) {
                wsn[q] = wsp[(kk + 8 + q) * NC];
                won[q] = wop[(kk + 8 + q) * NC];
            }
        }
#pragma unroll
        for (int q = 0; q < 8; ++q) {
            float4 xa = *(const float4*)&xt[kbase + kk + q][0];
            float4 xb = *(const float4*)&xt[kbase + kk + q][4];
            float ws = wsb[q], wo = wob[q];
            acs[0] = fmaf(xa.x, ws, acs[0]); aco[0] = fmaf(xa.x, wo, aco[0]);
            acs[1] = fmaf(xa.y, ws, acs[1]); aco[1] = fmaf(xa.y, wo, aco[1]);
            acs[2] = fmaf(xa.z, ws, acs[2]); aco[2] = fmaf(xa.z, wo, aco[2]);
            acs[3] = fmaf(xa.w, ws, acs[3]); aco[3] = fmaf(xa.w, wo, aco[3]);
            acs[4] = fmaf(xb.x, ws, acs[4]); aco[4] = fmaf(xb.x, wo, aco[4]);
            acs[5] = fmaf(xb.y, ws, acs[5]); aco[5] = fmaf(xb.y, wo, aco[5]);
            acs[6] = fmaf(xb.z, ws, acs[6]); aco[6] = fmaf(xb.z, wo, aco[6]);
            acs[7] = fmaf(xb.w, ws, acs[7]); aco[7] = fmaf(xb.w, wo, aco[7]);
        }
#pragma unroll
        for (int q = 0; q < 8; ++q) { wsb[q] = wsn[q]; wob[q] = won[q]; }
    }

    if (kh == 1) {
#pragma unroll
        for (int q = 0; q < 8; ++q) { red[c][q] = acs[q]; red[c][8 + q] = aco[q]; }
    }
    __syncthreads();
    if (kh == 0) {
        const float bsv = bs[c], bov = bo[c];
#pragma unroll
        for (int r = 0; r < 8; ++r) {
            subj[(size_t)(r0 + r) * NC + c] = acs[r] + red[c][r] + bsv;
            obj[(size_t)(r0 + r) * NC + c]  = aco[r] + red[c][8 + r] + bov;
        }
    }
}

// ---------------- K3: rep[b,i,j,h] = relu(sum_c |subj[j,c]-obj[i,c]| Wt[c,h] + bt[h])
// 32x64 (i,j) tile, grid = NB*16*8 = 512 (2 blocks/CU, 2 waves/SIMD).
// Per thread: 2i x 4j. LDS swizzled (+4 per 4-row group) => <=2-way everywhere.
// W_t via uniform scalar loads (off the LDS pipe).
#define OFS(r) ((r) * 68 + ((r) >> 2) * 4)
#define OFO(r) ((r) * 36 + ((r) >> 2) * 4)
__global__ __launch_bounds__(256) void k_rep(
    const float* __restrict__ subj, const float* __restrict__ obj,
    const float* __restrict__ Wt, const float* __restrict__ bt,
    float* __restrict__ attn) {
    const int bx = blockIdx.x;
    const int b = bx >> 7;
    const int rem = bx & 127;
    const int it = rem >> 3, jt = rem & 7;
    const int i0 = it * 32, j0 = jt * 64;

    __shared__ float sjT[4416];   // rows: c_local (64), cols: j (64), swizzled
    __shared__ float obT[2368];   // rows: c_local (64), cols: i (32), swizzled

    const int tid = threadIdx.x;
    const int tx = tid & 15;   // j group: j = j0 + 4*tx + jj
    const int ty = tid >> 4;   // i group: i = i0 + 2*ty + ii

    const float4* WtV = (const float4*)Wt;

    float acc[2][4][4];
#pragma unroll
    for (int ii = 0; ii < 2; ++ii)
#pragma unroll
        for (int jj = 0; jj < 4; ++jj)
#pragma unroll
            for (int h = 0; h < 4; ++h) acc[ii][jj][h] = 0.f;

    for (int cc = 0; cc < NC; cc += 64) {
        if (cc) __syncthreads();
        // stage subj tile (64 j-rows x 64 c) transposed+swizzled
#pragma unroll
        for (int p = 0; p < 4; ++p) {
            int u = p * 256 + tid;
            int j = u >> 4, c4 = u & 15;
            float4 vs = *(const float4*)(subj + ((size_t)(b * NT) + j0 + j) * NC + cc + c4 * 4);
            int rb = c4 * 4;
            sjT[OFS(rb + 0) + j] = vs.x;
            sjT[OFS(rb + 1) + j] = vs.y;
            sjT[OFS(rb + 2) + j] = vs.z;
            sjT[OFS(rb + 3) + j] = vs.w;
        }
        // stage obj tile (32 i-rows x 64 c)
#pragma unroll
        for (int p = 0; p < 2; ++p) {
            int u = p * 256 + tid;
            int i = u >> 4, c4 = u & 15;
            float4 vo = *(const float4*)(obj + ((size_t)(b * NT) + i0 + i) * NC + cc + c4 * 4);
            int rb = c4 * 4;
            obT[OFO(rb + 0) + i] = vo.x;
            obT[OFO(rb + 1) + i] = vo.y;
            obT[OFO(rb + 2) + i] = vo.z;
            obT[OFO(rb + 3) + i] = vo.w;
        }
        __syncthreads();

#pragma unroll 4
        for (int cl = 0; cl < 64; ++cl) {
            float4 s4 = *(const float4*)&sjT[OFS(cl) + tx * 4];
            float2 o2 = *(const float2*)&obT[OFO(cl) + ty * 2];
            float4 w4 = WtV[cc + cl];      // uniform -> s_load
            float sv[4] = {s4.x, s4.y, s4.z, s4.w};
            float ov[2] = {o2.x, o2.y};
#pragma unroll
            for (int ii = 0; ii < 2; ++ii)
#pragma unroll
                for (int jj = 0; jj < 4; ++jj) {
                    float d = fabsf(sv[jj] - ov[ii]);
                    acc[ii][jj][0] = fmaf(d, w4.x, acc[ii][jj][0]);
                    acc[ii][jj][1] = fmaf(d, w4.y, acc[ii][jj][1]);
                    acc[ii][jj][2] = fmaf(d, w4.z, acc[ii][jj][2]);
                    acc[ii][jj][3] = fmaf(d, w4.w, acc[ii][jj][3]);
                }
        }
    }

    const float4 btv = *(const float4*)bt;
#pragma unroll
    for (int ii = 0; ii < 2; ++ii) {
        const int i = i0 + ty * 2 + ii;
#pragma unroll
        for (int jj = 0; jj < 4; ++jj) {
            const int j = j0 + tx * 4 + jj;
            float4 r;
            r.x = fmaxf(acc[ii][jj][0] + btv.x, 0.f);
            r.y = fmaxf(acc[ii][jj][1] + btv.y, 0.f);
            r.z = fmaxf(acc[ii][jj][2] + btv.z, 0.f);
            r.w = fmaxf(acc[ii][jj][3] + btv.w, 0.f);
            *(float4*)&attn[(((size_t)b * NT + i) * NT + j) * NH] = r;
        }
    }
}

// ---------------- K4: softmax over j (per b,i,h) + post-softmax mask -------
__global__ void k_soft(float* __restrict__ attn, const int* __restrict__ mask) {
    const int bi = blockIdx.x;            // b*NT + i
    const int b = bi >> 9;
    float4* row = (float4*)(attn + (size_t)bi * (NT * NH));
    const int t = threadIdx.x;
    float4 v0 = row[t];
    float4 v1 = row[t + 256];

    float mx[4] = {fmaxf(v0.x, v1.x), fmaxf(v0.y, v1.y),
                   fmaxf(v0.z, v1.z), fmaxf(v0.w, v1.w)};
#pragma unroll
    for (int off = 32; off; off >>= 1) {
#pragma unroll
        for (int h = 0; h < 4; ++h) mx[h] = fmaxf(mx[h], __shfl_xor(mx[h], off));
    }
    __shared__ float redm[4][4], reds[4][4];
    const int wid = t >> 6, lane = t & 63;
    if (lane == 0) {
#pragma unroll
        for (int h = 0; h < 4; ++h) redm[wid][h] = mx[h];
    }
    __syncthreads();
#pragma unroll
    for (int h = 0; h < 4; ++h)
        mx[h] = fmaxf(fmaxf(redm[0][h], redm[1][h]), fmaxf(redm[2][h], redm[3][h]));

    float e0[4] = {expf(v0.x - mx[0]), expf(v0.y - mx[1]),
                   expf(v0.z - mx[2]), expf(v0.w - mx[3])};
    float e1[4] = {expf(v1.x - mx[0]), expf(v1.y - mx[1]),
                   expf(v1.z - mx[2]), expf(v1.w - mx[3])};
    float sm[4] = {e0[0] + e1[0], e0[1] + e1[1], e0[2] + e1[2], e0[3] + e1[3]};
#pragma unroll
    for (int off = 32; off; off >>= 1) {
#pragma unroll
        for (int h = 0; h < 4; ++h) sm[h] += __shfl_xor(sm[h], off);
    }
    if (lane == 0) {
#pragma unroll
        for (int h = 0; h < 4; ++h) reds[wid][h] = sm[h];
    }
    __syncthreads();
    float rinv[4];
#pragma unroll
    for (int h = 0; h < 4; ++h)
        rinv[h] = 1.0f / (reds[0][h] + reds[1][h] + reds[2][h] + reds[3][h]);

    const int mi = mask[bi];
    const int mj0 = mask[b * NT + t];
    const int mj1 = mask[b * NT + t + 256];
    float4 o0, o1;
    o0.x = (mi & mj0) ? 0.f : e0[0] * rinv[0];
    o0.y = (mi & mj0) ? 0.f : e0[1] * rinv[1];
    o0.z = (mi & mj0) ? 0.f : e0[2] * rinv[2];
    o0.w = (mi & mj0) ? 0.f : e0[3] * rinv[3];
    o1.x = (mi & mj1) ? 0.f : e1[0] * rinv[0];
    o1.y = (mi & mj1) ? 0.f : e1[1] * rinv[1];
    o1.z = (mi & mj1) ? 0.f : e1[2] * rinv[2];
    o1.w = (mi & mj1) ? 0.f : e1[3] * rinv[3];
    row[t] = o0;
    row[t + 256] = o1;
}

extern "C" void kernel_launch(void* const* d_in, const int* in_sizes, int n_in,
                              void* d_out, int out_size, void* d_ws, size_t ws_size,
                              hipStream_t stream) {
    const float* x      = (const float*)d_in[0];
    const float* W_subj = (const float*)d_in[1];
    const float* b_subj = (const float*)d_in[2];
    const float* W_obj  = (const float*)d_in[3];
    const float* b_obj  = (const float*)d_in[4];
    const float* W_t    = (const float*)d_in[5];
    const float* b_t    = (const float*)d_in[6];
    const unsigned char* mask_raw = (const unsigned char*)d_in[7];

    float* xnew = (float*)d_out;                           // NB*NT*NC2 floats
    float* attn = xnew + (size_t)NB * NT * NC2;            // NB*NT*NT*NH floats

    int* wmask  = (int*)d_ws;                              // NB*NT ints
    float* subj = (float*)d_ws + NB * NT;                  // NB*NT*NC
    float* obj  = subj + (size_t)NB * NT * NC;             // NB*NT*NC

    hipLaunchKernelGGL(k_mask, dim3(1), dim3(256), 0, stream, mask_raw, wmask);
    hipLaunchKernelGGL(k_poolproj, dim3(NB * NT / 8), dim3(512), 0, stream,
                       x, W_subj, b_subj, W_obj, b_obj, xnew, subj, obj);
    hipLaunchKernelGGL(k_rep, dim3(NB * 16 * 8), dim3(256), 0, stream,
                       subj, obj, W_t, b_t, attn);
    hipLaunchKernelGGL(k_soft, dim3(NB * NT), dim3(256), 0, stream, attn, wmask);
}